// Round 4
// baseline (65.874 us; speedup 1.0000x reference)
//
#include <hip/hip_runtime.h>
#include <hip/hip_bf16.h>

constexpr int B = 4;
constexpr int N = 50000;
constexpr int K = 128;
constexpr int S = 256;
constexpr int NCH = (N + 255) / 256;     // 196 chunks for error kernel
constexpr int SLICES = 128;              // point slices per batch (scan kernel)
constexpr int SLICE_PTS = (N + SLICES - 1) / SLICES;  // 391
constexpr float EPS = 1e-5f;

__device__ __forceinline__ float frcp  (float x) { return __builtin_amdgcn_rcpf(x); }
__device__ __forceinline__ float frsq  (float x) { return __builtin_amdgcn_rsqf(x); }
__device__ __forceinline__ float fsqrt_(float x) { return __builtin_amdgcn_sqrtf(x); }

// ---------------------------------------------------------------------------
// Static-indexed Jacobi solve (registers only — rule #20) shared by both paths
// ---------------------------------------------------------------------------
template<int P, int Q>
__device__ __forceinline__ void rot(float (&A)[4][4], float (&V)[4][4])
{
  const float apq = A[P][Q];
  const float theta = 0.5f * (A[Q][Q] - A[P][P]) * frcp(apq);
  const float tt = copysignf(
      frcp(fabsf(theta) + fsqrt_(fmaf(theta, theta, 1.f))), theta);
  float c  = frsq(fmaf(tt, tt, 1.f));
  float sn = tt * c;
  const bool tiny = fabsf(apq) < 1e-20f;
  c  = tiny ? 1.f : c;
  sn = tiny ? 0.f : sn;
  #pragma unroll
  for (int i = 0; i < 4; ++i) {
    const float aip = A[i][P], aiq = A[i][Q];
    A[i][P] = c * aip - sn * aiq;
    A[i][Q] = sn * aip + c * aiq;
  }
  #pragma unroll
  for (int i = 0; i < 4; ++i) {
    const float api = A[P][i], aqi = A[Q][i];
    A[P][i] = c * api - sn * aqi;
    A[Q][i] = sn * api + c * aqi;
  }
  #pragma unroll
  for (int i = 0; i < 4; ++i) {
    const float vip = V[i][P], viq = V[i][Q];
    V[i][P] = c * vip - sn * viq;
    V[i][Q] = sn * vip + c * viq;
  }
}

// Sm = {W, Σwp(3), Σwq(3), Σw p⊗q(9)}  ->  write 4x4 transform at To
__device__ __forceinline__ void solve_and_write(const float (&Sm)[16], float* To)
{
  const float W   = Sm[0];
  const float inv = frcp(W + EPS);
  const float scx = Sm[1]*inv, scy = Sm[2]*inv, scz = Sm[3]*inv;
  const float tcx = Sm[4]*inv, tcy = Sm[5]*inv, tcz = Sm[6]*inv;
  const float f = 2.f - W * inv;     // H = Σ(w s⊗t)·inv − (2−σ)·sc⊗tc
  const float Sxx = Sm[7]*inv  - f*scx*tcx;
  const float Sxy = Sm[8]*inv  - f*scx*tcy;
  const float Sxz = Sm[9]*inv  - f*scx*tcz;
  const float Syx = Sm[10]*inv - f*scy*tcx;
  const float Syy = Sm[11]*inv - f*scy*tcy;
  const float Syz = Sm[12]*inv - f*scy*tcz;
  const float Szx = Sm[13]*inv - f*scz*tcx;
  const float Szy = Sm[14]*inv - f*scz*tcy;
  const float Szz = Sm[15]*inv - f*scz*tcz;

  float A[4][4], V[4][4];
  A[0][0] = Sxx + Syy + Szz;
  A[0][1] = Syz - Szy;  A[0][2] = Szx - Sxz;  A[0][3] = Sxy - Syx;
  A[1][1] = Sxx - Syy - Szz;
  A[1][2] = Sxy + Syx;  A[1][3] = Szx + Sxz;
  A[2][2] = -Sxx + Syy - Szz;
  A[2][3] = Syz + Szy;
  A[3][3] = -Sxx - Syy + Szz;
  A[1][0] = A[0][1]; A[2][0] = A[0][2]; A[3][0] = A[0][3];
  A[2][1] = A[1][2]; A[3][1] = A[1][3]; A[3][2] = A[2][3];

  #pragma unroll
  for (int i = 0; i < 4; ++i)
    #pragma unroll
    for (int j = 0; j < 4; ++j) V[i][j] = (i == j) ? 1.f : 0.f;

  #pragma unroll 1
  for (int sweep = 0; sweep < 5; ++sweep) {
    rot<0,1>(A, V); rot<0,2>(A, V); rot<0,3>(A, V);
    rot<1,2>(A, V); rot<1,3>(A, V); rot<2,3>(A, V);
  }

  const float d0 = A[0][0], d1 = A[1][1], d2 = A[2][2], d3 = A[3][3];
  const bool b1 = d1 > d0;
  const bool b3 = d3 > d2;
  const bool bb = (b3 ? d3 : d2) > (b1 ? d1 : d0);
  float qw  = bb ? (b3 ? V[0][3] : V[0][2]) : (b1 ? V[0][1] : V[0][0]);
  float qxv = bb ? (b3 ? V[1][3] : V[1][2]) : (b1 ? V[1][1] : V[1][0]);
  float qyv = bb ? (b3 ? V[2][3] : V[2][2]) : (b1 ? V[2][1] : V[2][0]);
  float qzv = bb ? (b3 ? V[3][3] : V[3][2]) : (b1 ? V[3][1] : V[3][0]);

  const float qn = frsq(qw*qw + qxv*qxv + qyv*qyv + qzv*qzv);
  qw *= qn; qxv *= qn; qyv *= qn; qzv *= qn;

  const float R00 = 1.f - 2.f*(qyv*qyv + qzv*qzv);
  const float R01 = 2.f*(qxv*qyv - qw*qzv);
  const float R02 = 2.f*(qxv*qzv + qw*qyv);
  const float R10 = 2.f*(qxv*qyv + qw*qzv);
  const float R11 = 1.f - 2.f*(qxv*qxv + qzv*qzv);
  const float R12 = 2.f*(qyv*qzv - qw*qxv);
  const float R20 = 2.f*(qxv*qzv - qw*qyv);
  const float R21 = 2.f*(qyv*qzv + qw*qxv);
  const float R22 = 1.f - 2.f*(qxv*qxv + qyv*qyv);

  const float tx = tcx - (R00*scx + R01*scy + R02*scz);
  const float ty = tcy - (R10*scx + R11*scy + R12*scz);
  const float tz = tcz - (R20*scx + R21*scy + R22*scz);

  float4* T4 = (float4*)To;
  T4[0] = make_float4(R00, R01, R02, tx);
  T4[1] = make_float4(R10, R11, R12, ty);
  T4[2] = make_float4(R20, R21, R22, tz);
  T4[3] = make_float4(0.f, 0.f, 0.f, 1.f);
}

// ---------------------------------------------------------------------------
// Kernel 1 (NEW): slice-scan. Inverts the gather: block = (batch b, slice of
// 391 contiguous points staged in LDS). Scan the whole sel array linearly
// (L2-resident, coalesced int4 loads); for each entry hitting this slice,
// accumulate the 16 weighted moments into per-k LDS accumulators (atomicAdd).
// Converts 131k random L3/HBM line-fills (the measured ~30µs hog, ~4-8
// concurrent fills/CU) into pure linear streams + on-chip LDS traffic.
// ---------------------------------------------------------------------------
__global__ __launch_bounds__(256) void scan_kernel(
    const float* __restrict__ src, const float* __restrict__ tgt,
    const float* __restrict__ wts, const int* __restrict__ sel,
    float* __restrict__ part)
{
  __shared__ float4 sp[SLICE_PTS];       // (p.xyz, w)
  __shared__ float4 sq[SLICE_PTS];       // (q.xyz, -)
  __shared__ float  t_sums[K * 16];      // per-k moment accumulators

  const int bid   = blockIdx.x;
  const int xcd   = bid & 7;
  const int b     = xcd >> 1;                       // batch pinned to XCD pair
  const int slice = ((bid >> 3) << 1) | (xcd & 1);  // [0,128)
  const int tid   = threadIdx.x;

  const int lo  = slice * SLICE_PTS;
  const int cnt = min(SLICE_PTS, N - lo);           // last slice: 343

  // stage slice points (linear, coalesced-ish scalar loads)
  for (int i = tid; i < cnt; i += 256) {
    const int p = b * N + lo + i;
    sp[i] = make_float4(src[3*p], src[3*p+1], src[3*p+2], wts[p]);
    sq[i] = make_float4(tgt[3*p], tgt[3*p+1], tgt[3*p+2], 0.f);
  }
  #pragma unroll
  for (int z = 0; z < 8; ++z) t_sums[tid * 8 + z] = 0.f;
  __syncthreads();

  // scan all K*S = 32768 sel entries, 4 at a time (int4), strided by thread
  const int4* sel4 = (const int4*)sel;
  #pragma unroll 2
  for (int it = 0; it < (K * S / 4) / 256; ++it) {   // 32 iterations
    const int j4 = it * 256 + tid;
    const int4 sv = sel4[j4];
    #pragma unroll
    for (int e = 0; e < 4; ++e) {
      const int idx = (e == 0) ? sv.x : (e == 1) ? sv.y : (e == 2) ? sv.z : sv.w;
      const unsigned d = (unsigned)(idx - lo);
      if (d < (unsigned)cnt) {
        const int j = j4 * 4 + e;
        const int k = j >> 8;                        // row of sel = k
        const float4 P = sp[d];
        const float4 Q = sq[d];
        const float w = P.w;
        float* ts = t_sums + k * 16;
        atomicAdd(ts + 0,  w);
        atomicAdd(ts + 1,  w * P.x);
        atomicAdd(ts + 2,  w * P.y);
        atomicAdd(ts + 3,  w * P.z);
        atomicAdd(ts + 4,  w * Q.x);
        atomicAdd(ts + 5,  w * Q.y);
        atomicAdd(ts + 6,  w * Q.z);
        atomicAdd(ts + 7,  w * P.x * Q.x);
        atomicAdd(ts + 8,  w * P.x * Q.y);
        atomicAdd(ts + 9,  w * P.x * Q.z);
        atomicAdd(ts + 10, w * P.y * Q.x);
        atomicAdd(ts + 11, w * P.y * Q.y);
        atomicAdd(ts + 12, w * P.y * Q.z);
        atomicAdd(ts + 13, w * P.z * Q.x);
        atomicAdd(ts + 14, w * P.z * Q.y);
        atomicAdd(ts + 15, w * P.z * Q.z);
      }
    }
  }
  __syncthreads();

  // write 2048 partial floats, coalesced (two float4 per thread)
  float4* p4 = (float4*)(part + ((size_t)(b * SLICES + slice)) * (K * 16));
  const float4* t4 = (const float4*)t_sums;
  p4[tid * 2]     = t4[tid * 2];
  p4[tid * 2 + 1] = t4[tid * 2 + 1];
}

// ---------------------------------------------------------------------------
// Kernel 2 (NEW): reduce partials over 128 slices (fixed order -> deterministic
// association) + fused static-register Jacobi solve. One block per (b,k).
// ---------------------------------------------------------------------------
__global__ __launch_bounds__(256) void reduce_solve_kernel(
    const float* __restrict__ part, float* __restrict__ T)
{
  const int bid = blockIdx.x;
  const int b   = bid >> 7;
  const int k   = bid & (K - 1);
  const int tid = threadIdx.x;
  const int i   = tid & 15;        // moment index
  const int sg  = tid >> 4;        // slice group [0,16)

  float sum = 0.f;
  #pragma unroll
  for (int m = 0; m < SLICES / 16; ++m) {    // 8 independent loads (MLP)
    const int slice = sg + 16 * m;
    sum += part[((size_t)(b * SLICES + slice)) * (K * 16) + k * 16 + i];
  }

  __shared__ float red[16][17];
  red[sg][i] = sum;
  __syncthreads();

  __shared__ float SmS[16];
  if (tid < 16) {
    float t = 0.f;
    #pragma unroll
    for (int g = 0; g < 16; ++g) t += red[g][tid];
    SmS[tid] = t;
  }
  __syncthreads();

  if (tid == 0) {
    float Sm[16];
    #pragma unroll
    for (int z = 0; z < 16; ++z) Sm[z] = SmS[z];
    solve_and_write(Sm, T + (size_t)(b * K + k) * 16);
  }
}

// ---------------------------------------------------------------------------
// Fallback fit path (small-ws): R3's gather_reduce + solve (raw arrays)
// ---------------------------------------------------------------------------
__global__ __launch_bounds__(256) void gather_reduce_kernel(
    const float* __restrict__ src, const float* __restrict__ tgt,
    const float* __restrict__ wts, const int* __restrict__ sel,
    float* __restrict__ sums)
{
  const int bid = blockIdx.x;
  const int xcd = bid & 7;
  const int b   = xcd >> 1;
  const int k   = ((bid >> 3) << 1) | (xcd & 1);
  const int s   = threadIdx.x;

  const int idx = sel[k * S + s];
  const float* ps = src + (size_t)(b * N + idx) * 3;
  const float* pt = tgt + (size_t)(b * N + idx) * 3;
  const float w  = wts[b * N + idx];
  const float px = ps[0], py = ps[1], pz = ps[2];
  const float qx = pt[0], qy = pt[1], qz = pt[2];

  float acc[16];
  acc[0] = w;
  acc[1] = w * px;  acc[2] = w * py;  acc[3] = w * pz;
  acc[4] = w * qx;  acc[5] = w * qy;  acc[6] = w * qz;
  acc[7]  = w * px * qx; acc[8]  = w * px * qy; acc[9]  = w * px * qz;
  acc[10] = w * py * qx; acc[11] = w * py * qy; acc[12] = w * py * qz;
  acc[13] = w * pz * qx; acc[14] = w * pz * qy; acc[15] = w * pz * qz;

  #pragma unroll
  for (int off = 32; off > 0; off >>= 1) {
    #pragma unroll
    for (int i = 0; i < 16; ++i)
      acc[i] += __shfl_down(acc[i], off);
  }

  __shared__ float red[4][16];
  const int lane = threadIdx.x & 63, wv = threadIdx.x >> 6;
  if (lane == 0) {
    #pragma unroll
    for (int i = 0; i < 16; ++i) red[wv][i] = acc[i];
  }
  __syncthreads();
  if (threadIdx.x == 0) {
    float Sm[16];
    #pragma unroll
    for (int i = 0; i < 16; ++i)
      Sm[i] = red[0][i] + red[1][i] + red[2][i] + red[3][i];
    solve_and_write(Sm, sums + (size_t)(b * K + k) * 16);  // sums == T here
  }
}

// ---------------------------------------------------------------------------
// Kernel 3: error evaluation (unchanged structure, raw inputs). KPT=4
// transforms/thread amortizes each LDS point broadcast 4x.
// ---------------------------------------------------------------------------
constexpr int KPT = 4;
constexpr int KG  = K / KPT;      // 32
constexpr int NSL = 256 / KG;     // 8
constexpr int PPS = 256 / NSL;    // 32

__global__ __launch_bounds__(256) void error_kernel(
    const float* __restrict__ src, const float* __restrict__ tgt,
    const float* __restrict__ wts, const float* __restrict__ T,
    float* __restrict__ partial)
{
  __shared__ float4 sp[256];
  __shared__ float4 sq[256];
  __shared__ float  t4[K][12];
  __shared__ float  red[K][NSL + 1];

  const int blk = blockIdx.x;
  const int b   = blk / NCH;
  const int ch  = blk - b * NCH;
  const int tid = threadIdx.x;
  const int j   = ch * 256 + tid;

  float4 P = make_float4(0.f, 0.f, 0.f, 0.f);
  float4 Q = make_float4(0.f, 0.f, 0.f, 0.f);
  if (j < N) {
    const float* ps = src + (size_t)(b*N + j) * 3;
    const float* pt = tgt + (size_t)(b*N + j) * 3;
    P.x = ps[0]; P.y = ps[1]; P.z = ps[2]; P.w = wts[b*N + j];
    Q.x = pt[0]; Q.y = pt[1]; Q.z = pt[2];
  }
  sp[tid] = P; sq[tid] = Q;

  if (tid < K) {
    const float* tp = T + (size_t)(b*K + tid) * 16;
    #pragma unroll
    for (int c = 0; c < 12; ++c) t4[tid][c] = tp[c];
  }
  __syncthreads();

  const int kg    = tid & (KG - 1);
  const int slice = tid >> 5;

  float R[KPT][12];
  #pragma unroll
  for (int m = 0; m < KPT; ++m) {
    const int k = kg + m * KG;
    #pragma unroll
    for (int c = 0; c < 12; ++c) R[m][c] = t4[k][c];
  }

  float acc[KPT] = {0.f, 0.f, 0.f, 0.f};
  const int base = slice * PPS;
  #pragma unroll 4
  for (int i = 0; i < PPS; ++i) {
    const float4 p = sp[base + i];
    const float4 q = sq[base + i];
    #pragma unroll
    for (int m = 0; m < KPT; ++m) {
      const float dx = fmaf(R[m][0], p.x, fmaf(R[m][1], p.y, fmaf(R[m][2],  p.z, R[m][3])))  - q.x;
      const float dy = fmaf(R[m][4], p.x, fmaf(R[m][5], p.y, fmaf(R[m][6],  p.z, R[m][7])))  - q.y;
      const float dz = fmaf(R[m][8], p.x, fmaf(R[m][9], p.y, fmaf(R[m][10], p.z, R[m][11]))) - q.z;
      const float d2 = fmaf(dx, dx, fmaf(dy, dy, dz*dz));
      acc[m] = fmaf(p.w, fsqrt_(d2), acc[m]);
    }
  }

  #pragma unroll
  for (int m = 0; m < KPT; ++m)
    red[kg + m * KG][slice] = acc[m];
  __syncthreads();

  if (tid < K) {
    float sum = 0.f;
    #pragma unroll
    for (int s2 = 0; s2 < NSL; ++s2) sum += red[tid][s2];
    partial[((size_t)b * NCH + ch) * K + tid] = sum;
  }
}

// ---------------------------------------------------------------------------
// Kernel 4: argmin (NOW latency-parallel: 2 threads/k, independent unrolled
// loads instead of a 196-step dependent chain). Fixed summation order.
// ---------------------------------------------------------------------------
__global__ __launch_bounds__(256) void argmin_kernel(
    const float* __restrict__ partial, const float* __restrict__ T,
    float* __restrict__ out)
{
  const int b   = blockIdx.x;
  const int tid = threadIdx.x;
  const int k   = tid & (K - 1);
  const int h   = tid >> 7;          // 0: even chunks, 1: odd chunks

  float sum = 0.f;
  #pragma unroll 7
  for (int c = h; c < NCH; c += 2)
    sum += partial[((size_t)b * NCH + c) * K + k];

  __shared__ float vals[256];
  __shared__ int   idxs[K];
  vals[tid] = sum;
  __syncthreads();

  if (tid < K) { vals[tid] = vals[tid] + vals[tid + K]; idxs[tid] = tid; }
  __syncthreads();

  for (int off = K / 2; off > 0; off >>= 1) {
    if (tid < off) {
      const float o = vals[tid + off];
      if (o < vals[tid] || (o == vals[tid] && idxs[tid + off] < idxs[tid])) {
        vals[tid] = o; idxs[tid] = idxs[tid + off];
      }
    }
    __syncthreads();
  }

  const int best = idxs[0];
  if (tid < 16) out[(size_t)b * 16 + tid] = T[(size_t)(b * K + best) * 16 + tid];
}

// ---------------------------------------------------------------------------
extern "C" void kernel_launch(void* const* d_in, const int* in_sizes, int n_in,
                              void* d_out, int out_size, void* d_ws, size_t ws_size,
                              hipStream_t stream) {
  const float* src = (const float*)d_in[0];
  const float* tgt = (const float*)d_in[1];
  const float* wts = (const float*)d_in[2];
  const int*   sel = (const int*)d_in[3];

  const size_t part_floats    = (size_t)B * SLICES * K * 16;   // 4M floats
  const size_t T_floats       = (size_t)B * K * 16;            // 8192
  const size_t partial_floats = (size_t)B * NCH * K;           // 100352
  const bool fast = ws_size >=
      (part_floats + T_floats + partial_floats) * sizeof(float);

  if (fast) {
    float* part    = (float*)d_ws;
    float* T       = part + part_floats;
    float* partial = T + T_floats;

    scan_kernel<<<B * SLICES, 256, 0, stream>>>(src, tgt, wts, sel, part);
    reduce_solve_kernel<<<B * K, 256, 0, stream>>>(part, T);
    error_kernel<<<B * NCH, 256, 0, stream>>>(src, tgt, wts, T, partial);
    argmin_kernel<<<B, 256, 0, stream>>>(partial, T, (float*)d_out);
  } else {
    float* T       = (float*)d_ws;
    float* partial = T + T_floats;

    gather_reduce_kernel<<<B * K, 256, 0, stream>>>(src, tgt, wts, sel, T);
    error_kernel<<<B * NCH, 256, 0, stream>>>(src, tgt, wts, T, partial);
    argmin_kernel<<<B, 256, 0, stream>>>(partial, T, (float*)d_out);
  }
}

// Round 5
// 65.257 us; speedup vs baseline: 1.0095x; 1.0095x over previous
//
#include <hip/hip_runtime.h>
#include <hip/hip_bf16.h>

constexpr int B = 4;
constexpr int N = 50000;
constexpr int K = 128;
constexpr int S = 256;
constexpr int NCH = (N + 255) / 256;     // 196 chunks for error kernel
constexpr int SLICES = 128;              // point slices per batch (scan kernel)
constexpr int SLICE_PTS = (N + SLICES - 1) / SLICES;  // 391
constexpr float EPS = 1e-5f;

__device__ __forceinline__ float frcp  (float x) { return __builtin_amdgcn_rcpf(x); }
__device__ __forceinline__ float frsq  (float x) { return __builtin_amdgcn_rsqf(x); }
__device__ __forceinline__ float fsqrt_(float x) { return __builtin_amdgcn_sqrtf(x); }

// ---------------------------------------------------------------------------
// Static-indexed Jacobi solve (registers only — rule #20)
// ---------------------------------------------------------------------------
template<int P, int Q>
__device__ __forceinline__ void rot(float (&A)[4][4], float (&V)[4][4])
{
  const float apq = A[P][Q];
  const float theta = 0.5f * (A[Q][Q] - A[P][P]) * frcp(apq);
  const float tt = copysignf(
      frcp(fabsf(theta) + fsqrt_(fmaf(theta, theta, 1.f))), theta);
  float c  = frsq(fmaf(tt, tt, 1.f));
  float sn = tt * c;
  const bool tiny = fabsf(apq) < 1e-20f;
  c  = tiny ? 1.f : c;
  sn = tiny ? 0.f : sn;
  #pragma unroll
  for (int i = 0; i < 4; ++i) {
    const float aip = A[i][P], aiq = A[i][Q];
    A[i][P] = c * aip - sn * aiq;
    A[i][Q] = sn * aip + c * aiq;
  }
  #pragma unroll
  for (int i = 0; i < 4; ++i) {
    const float api = A[P][i], aqi = A[Q][i];
    A[P][i] = c * api - sn * aqi;
    A[Q][i] = sn * api + c * aqi;
  }
  #pragma unroll
  for (int i = 0; i < 4; ++i) {
    const float vip = V[i][P], viq = V[i][Q];
    V[i][P] = c * vip - sn * viq;
    V[i][Q] = sn * vip + c * viq;
  }
}

// Sm = {W, Σwp(3), Σwq(3), Σw p⊗q(9)}  ->  write 4x4 transform at To
__device__ __forceinline__ void solve_and_write(const float (&Sm)[16], float* To)
{
  const float W   = Sm[0];
  const float inv = frcp(W + EPS);
  const float scx = Sm[1]*inv, scy = Sm[2]*inv, scz = Sm[3]*inv;
  const float tcx = Sm[4]*inv, tcy = Sm[5]*inv, tcz = Sm[6]*inv;
  const float f = 2.f - W * inv;     // H = Σ(w s⊗t)·inv − (2−σ)·sc⊗tc
  const float Sxx = Sm[7]*inv  - f*scx*tcx;
  const float Sxy = Sm[8]*inv  - f*scx*tcy;
  const float Sxz = Sm[9]*inv  - f*scx*tcz;
  const float Syx = Sm[10]*inv - f*scy*tcx;
  const float Syy = Sm[11]*inv - f*scy*tcy;
  const float Syz = Sm[12]*inv - f*scy*tcz;
  const float Szx = Sm[13]*inv - f*scz*tcx;
  const float Szy = Sm[14]*inv - f*scz*tcy;
  const float Szz = Sm[15]*inv - f*scz*tcz;

  float A[4][4], V[4][4];
  A[0][0] = Sxx + Syy + Szz;
  A[0][1] = Syz - Szy;  A[0][2] = Szx - Sxz;  A[0][3] = Sxy - Syx;
  A[1][1] = Sxx - Syy - Szz;
  A[1][2] = Sxy + Syx;  A[1][3] = Szx + Sxz;
  A[2][2] = -Sxx + Syy - Szz;
  A[2][3] = Syz + Szy;
  A[3][3] = -Sxx - Syy + Szz;
  A[1][0] = A[0][1]; A[2][0] = A[0][2]; A[3][0] = A[0][3];
  A[2][1] = A[1][2]; A[3][1] = A[1][3]; A[3][2] = A[2][3];

  #pragma unroll
  for (int i = 0; i < 4; ++i)
    #pragma unroll
    for (int j = 0; j < 4; ++j) V[i][j] = (i == j) ? 1.f : 0.f;

  #pragma unroll 1
  for (int sweep = 0; sweep < 5; ++sweep) {
    rot<0,1>(A, V); rot<0,2>(A, V); rot<0,3>(A, V);
    rot<1,2>(A, V); rot<1,3>(A, V); rot<2,3>(A, V);
  }

  const float d0 = A[0][0], d1 = A[1][1], d2 = A[2][2], d3 = A[3][3];
  const bool b1 = d1 > d0;
  const bool b3 = d3 > d2;
  const bool bb = (b3 ? d3 : d2) > (b1 ? d1 : d0);
  float qw  = bb ? (b3 ? V[0][3] : V[0][2]) : (b1 ? V[0][1] : V[0][0]);
  float qxv = bb ? (b3 ? V[1][3] : V[1][2]) : (b1 ? V[1][1] : V[1][0]);
  float qyv = bb ? (b3 ? V[2][3] : V[2][2]) : (b1 ? V[2][1] : V[2][0]);
  float qzv = bb ? (b3 ? V[3][3] : V[3][2]) : (b1 ? V[3][1] : V[3][0]);

  const float qn = frsq(qw*qw + qxv*qxv + qyv*qyv + qzv*qzv);
  qw *= qn; qxv *= qn; qyv *= qn; qzv *= qn;

  const float R00 = 1.f - 2.f*(qyv*qyv + qzv*qzv);
  const float R01 = 2.f*(qxv*qyv - qw*qzv);
  const float R02 = 2.f*(qxv*qzv + qw*qyv);
  const float R10 = 2.f*(qxv*qyv + qw*qzv);
  const float R11 = 1.f - 2.f*(qxv*qxv + qzv*qzv);
  const float R12 = 2.f*(qyv*qzv - qw*qxv);
  const float R20 = 2.f*(qxv*qzv - qw*qyv);
  const float R21 = 2.f*(qyv*qzv + qw*qxv);
  const float R22 = 1.f - 2.f*(qxv*qxv + qyv*qyv);

  const float tx = tcx - (R00*scx + R01*scy + R02*scz);
  const float ty = tcy - (R10*scx + R11*scy + R12*scz);
  const float tz = tcz - (R20*scx + R21*scy + R22*scz);

  float4* T4 = (float4*)To;
  T4[0] = make_float4(R00, R01, R02, tx);
  T4[1] = make_float4(R10, R11, R12, ty);
  T4[2] = make_float4(R20, R21, R22, tz);
  T4[3] = make_float4(0.f, 0.f, 0.f, 1.f);
}

// ---------------------------------------------------------------------------
// Kernel 1 (REWORKED scan): block = (batch b, slice of 391 contiguous points).
// Differences vs the R4 regression: NO atomics (thread-per-k register
// accumulators), sel staged ONCE per block in LDS as ushort (2-way-conflict
// reads = free), branchy hit-body (~0.4 wave-activation, ~4 active lanes).
// Zero scattered global traffic -> sidesteps the measured ~30µs random-line
// wall (~4.4 G-lines/s chip-wide, invariant across R1-R3).
// LDS = 78.6KB -> exactly 2 blocks/CU (8 waves).
// ---------------------------------------------------------------------------
constexpr int SEL_ROW = 258;   // ushorts per padded row (dword-aligned pairs)
constexpr int PT_BYTES  = SLICE_PTS * 16 * 2;          // sp + sq  = 12512
constexpr int SEL_BYTES = K * SEL_ROW * 2;             // 66048
constexpr int SMEM_BYTES = PT_BYTES + SEL_BYTES;       // 78560

__global__ __launch_bounds__(256) void scan_kernel(
    const float* __restrict__ src, const float* __restrict__ tgt,
    const float* __restrict__ wts, const int* __restrict__ sel,
    float* __restrict__ part)
{
  __shared__ __align__(16) char smem[SMEM_BYTES];
  float4* sp = (float4*)smem;                      // [391] (p.xyz, w)
  float4* sq = sp + SLICE_PTS;                     // [391] (q.xyz, -)
  unsigned short* sl = (unsigned short*)(smem + PT_BYTES);  // [128][258]
  float* red2 = (float*)smem;                      // overlay AFTER scan: [128][17]

  const int bid   = blockIdx.x;
  const int xcd   = bid & 7;
  const int b     = xcd >> 1;                       // batch pinned to XCD pair
  const int slice = ((bid >> 3) << 1) | (xcd & 1);  // bijective over [0,128)
  const int tid   = threadIdx.x;

  const int lo  = slice * SLICE_PTS;
  const int cnt = min(SLICE_PTS, N - lo);           // last slice: 343

  // stage slice points (linear loads)
  for (int i = tid; i < cnt; i += 256) {
    const int p = b * N + lo + i;
    sp[i] = make_float4(src[3*p], src[3*p+1], src[3*p+2], wts[p]);
    sq[i] = make_float4(tgt[3*p], tgt[3*p+1], tgt[3*p+2], 0.f);
  }
  // stage sel as ushort, rows padded to 258 (values < 50000 < 65536)
  {
    const int4* sel4 = (const int4*)sel;
    unsigned int* dst = (unsigned int*)sl;
    #pragma unroll 4
    for (int it = 0; it < (K * S / 4) / 256; ++it) {   // 32 iterations
      const int i4 = it * 256 + tid;                   // int4 index
      const int4 sv = sel4[i4];
      const int k  = i4 >> 6;                          // 64 int4s per row
      const int s0 = (i4 & 63) * 4;
      const int dw = k * (SEL_ROW / 2) + (s0 >> 1);
      dst[dw]     = (sv.x & 0xFFFF) | (sv.y << 16);
      dst[dw + 1] = (sv.z & 0xFFFF) | (sv.w << 16);
    }
  }
  __syncthreads();

  const int k  = tid & (K - 1);
  const int sh = tid >> 7;            // s-half: [0,128) or [128,256)

  float acc[16];
  #pragma unroll
  for (int i = 0; i < 16; ++i) acc[i] = 0.f;

  const unsigned short* row = sl + k * SEL_ROW + sh * 128;
  #pragma unroll 4
  for (int s = 0; s < 128; ++s) {
    const int idx = row[s];                    // ds_read_u16, 2-way conflict
    const unsigned d = (unsigned)(idx - lo);
    if (d < (unsigned)cnt) {                   // ~0.4 wave-activation
      const float4 P = sp[d];
      const float4 Q = sq[d];
      const float w = P.w;
      acc[0]  += w;
      acc[1]  = fmaf(w, P.x, acc[1]);
      acc[2]  = fmaf(w, P.y, acc[2]);
      acc[3]  = fmaf(w, P.z, acc[3]);
      acc[4]  = fmaf(w, Q.x, acc[4]);
      acc[5]  = fmaf(w, Q.y, acc[5]);
      acc[6]  = fmaf(w, Q.z, acc[6]);
      const float wx = w * P.x, wy = w * P.y, wz = w * P.z;
      acc[7]  = fmaf(wx, Q.x, acc[7]);
      acc[8]  = fmaf(wx, Q.y, acc[8]);
      acc[9]  = fmaf(wx, Q.z, acc[9]);
      acc[10] = fmaf(wy, Q.x, acc[10]);
      acc[11] = fmaf(wy, Q.y, acc[11]);
      acc[12] = fmaf(wy, Q.z, acc[12]);
      acc[13] = fmaf(wz, Q.x, acc[13]);
      acc[14] = fmaf(wz, Q.y, acc[14]);
      acc[15] = fmaf(wz, Q.z, acc[15]);
    }
  }
  __syncthreads();                    // points dead; red2 overlays sp/sq

  if (sh == 0) {
    #pragma unroll
    for (int c = 0; c < 16; ++c) red2[k * 17 + c] = acc[c];
  }
  __syncthreads();
  if (sh == 1) {
    #pragma unroll
    for (int c = 0; c < 16; ++c) red2[k * 17 + c] += acc[c];
  }
  __syncthreads();

  // write 2048 floats coalesced (8 consecutive floats per thread)
  float* out = part + ((size_t)(b * SLICES + slice)) * (K * 16);
  #pragma unroll
  for (int u = 0; u < 8; ++u) {
    const int fl = tid * 8 + u;
    out[fl] = red2[(fl >> 4) * 17 + (fl & 15)];
  }
}

// ---------------------------------------------------------------------------
// Kernel 2: reduce partials over 128 slices (fixed order -> deterministic)
// + fused static-register Jacobi solve. One block per (b,k).
// ---------------------------------------------------------------------------
__global__ __launch_bounds__(256) void reduce_solve_kernel(
    const float* __restrict__ part, float* __restrict__ T)
{
  const int bid = blockIdx.x;
  const int b   = bid >> 7;
  const int k   = bid & (K - 1);
  const int tid = threadIdx.x;
  const int i   = tid & 15;        // moment index
  const int sg  = tid >> 4;        // slice group [0,16)

  float sum = 0.f;
  #pragma unroll
  for (int m = 0; m < SLICES / 16; ++m) {    // 8 independent loads (MLP)
    const int slice = sg + 16 * m;
    sum += part[((size_t)(b * SLICES + slice)) * (K * 16) + k * 16 + i];
  }

  __shared__ float red[16][17];
  red[sg][i] = sum;
  __syncthreads();

  __shared__ float SmS[16];
  if (tid < 16) {
    float t = 0.f;
    #pragma unroll
    for (int g = 0; g < 16; ++g) t += red[g][tid];
    SmS[tid] = t;
  }
  __syncthreads();

  if (tid == 0) {
    float Sm[16];
    #pragma unroll
    for (int z = 0; z < 16; ++z) Sm[z] = SmS[z];
    solve_and_write(Sm, T + (size_t)(b * K + k) * 16);
  }
}

// ---------------------------------------------------------------------------
// Fallback fit path (small-ws): gather + solve
// ---------------------------------------------------------------------------
__global__ __launch_bounds__(256) void gather_reduce_kernel(
    const float* __restrict__ src, const float* __restrict__ tgt,
    const float* __restrict__ wts, const int* __restrict__ sel,
    float* __restrict__ sums)
{
  const int bid = blockIdx.x;
  const int xcd = bid & 7;
  const int b   = xcd >> 1;
  const int k   = ((bid >> 3) << 1) | (xcd & 1);
  const int s   = threadIdx.x;

  const int idx = sel[k * S + s];
  const float* ps = src + (size_t)(b * N + idx) * 3;
  const float* pt = tgt + (size_t)(b * N + idx) * 3;
  const float w  = wts[b * N + idx];
  const float px = ps[0], py = ps[1], pz = ps[2];
  const float qx = pt[0], qy = pt[1], qz = pt[2];

  float acc[16];
  acc[0] = w;
  acc[1] = w * px;  acc[2] = w * py;  acc[3] = w * pz;
  acc[4] = w * qx;  acc[5] = w * qy;  acc[6] = w * qz;
  acc[7]  = w * px * qx; acc[8]  = w * px * qy; acc[9]  = w * px * qz;
  acc[10] = w * py * qx; acc[11] = w * py * qy; acc[12] = w * py * qz;
  acc[13] = w * pz * qx; acc[14] = w * pz * qy; acc[15] = w * pz * qz;

  #pragma unroll
  for (int off = 32; off > 0; off >>= 1) {
    #pragma unroll
    for (int i = 0; i < 16; ++i)
      acc[i] += __shfl_down(acc[i], off);
  }

  __shared__ float red[4][16];
  const int lane = threadIdx.x & 63, wv = threadIdx.x >> 6;
  if (lane == 0) {
    #pragma unroll
    for (int i = 0; i < 16; ++i) red[wv][i] = acc[i];
  }
  __syncthreads();
  if (threadIdx.x == 0) {
    float Sm[16];
    #pragma unroll
    for (int i = 0; i < 16; ++i)
      Sm[i] = red[0][i] + red[1][i] + red[2][i] + red[3][i];
    solve_and_write(Sm, sums + (size_t)(b * K + k) * 16);
  }
}

// ---------------------------------------------------------------------------
// Kernel 3: error evaluation (unchanged; near its VALU roofline ~5.5µs)
// ---------------------------------------------------------------------------
constexpr int KPT = 4;
constexpr int KG  = K / KPT;      // 32
constexpr int NSL = 256 / KG;     // 8
constexpr int PPS = 256 / NSL;    // 32

__global__ __launch_bounds__(256) void error_kernel(
    const float* __restrict__ src, const float* __restrict__ tgt,
    const float* __restrict__ wts, const float* __restrict__ T,
    float* __restrict__ partial)
{
  __shared__ float4 sp[256];
  __shared__ float4 sq[256];
  __shared__ float  t4[K][12];
  __shared__ float  red[K][NSL + 1];

  const int blk = blockIdx.x;
  const int b   = blk / NCH;
  const int ch  = blk - b * NCH;
  const int tid = threadIdx.x;
  const int j   = ch * 256 + tid;

  float4 P = make_float4(0.f, 0.f, 0.f, 0.f);
  float4 Q = make_float4(0.f, 0.f, 0.f, 0.f);
  if (j < N) {
    const float* ps = src + (size_t)(b*N + j) * 3;
    const float* pt = tgt + (size_t)(b*N + j) * 3;
    P.x = ps[0]; P.y = ps[1]; P.z = ps[2]; P.w = wts[b*N + j];
    Q.x = pt[0]; Q.y = pt[1]; Q.z = pt[2];
  }
  sp[tid] = P; sq[tid] = Q;

  if (tid < K) {
    const float* tp = T + (size_t)(b*K + tid) * 16;
    #pragma unroll
    for (int c = 0; c < 12; ++c) t4[tid][c] = tp[c];
  }
  __syncthreads();

  const int kg    = tid & (KG - 1);
  const int slice = tid >> 5;

  float R[KPT][12];
  #pragma unroll
  for (int m = 0; m < KPT; ++m) {
    const int k = kg + m * KG;
    #pragma unroll
    for (int c = 0; c < 12; ++c) R[m][c] = t4[k][c];
  }

  float acc[KPT] = {0.f, 0.f, 0.f, 0.f};
  const int base = slice * PPS;
  #pragma unroll 4
  for (int i = 0; i < PPS; ++i) {
    const float4 p = sp[base + i];
    const float4 q = sq[base + i];
    #pragma unroll
    for (int m = 0; m < KPT; ++m) {
      const float dx = fmaf(R[m][0], p.x, fmaf(R[m][1], p.y, fmaf(R[m][2],  p.z, R[m][3])))  - q.x;
      const float dy = fmaf(R[m][4], p.x, fmaf(R[m][5], p.y, fmaf(R[m][6],  p.z, R[m][7])))  - q.y;
      const float dz = fmaf(R[m][8], p.x, fmaf(R[m][9], p.y, fmaf(R[m][10], p.z, R[m][11]))) - q.z;
      const float d2 = fmaf(dx, dx, fmaf(dy, dy, dz*dz));
      acc[m] = fmaf(p.w, fsqrt_(d2), acc[m]);
    }
  }

  #pragma unroll
  for (int m = 0; m < KPT; ++m)
    red[kg + m * KG][slice] = acc[m];
  __syncthreads();

  if (tid < K) {
    float sum = 0.f;
    #pragma unroll
    for (int s2 = 0; s2 < NSL; ++s2) sum += red[tid][s2];
    partial[((size_t)b * NCH + ch) * K + tid] = sum;
  }
}

// ---------------------------------------------------------------------------
// Kernel 4: argmin (latency-parallel partial sum, fixed order, first-
// occurrence tie-break), copy winning transform.
// ---------------------------------------------------------------------------
__global__ __launch_bounds__(256) void argmin_kernel(
    const float* __restrict__ partial, const float* __restrict__ T,
    float* __restrict__ out)
{
  const int b   = blockIdx.x;
  const int tid = threadIdx.x;
  const int k   = tid & (K - 1);
  const int h   = tid >> 7;

  float sum = 0.f;
  #pragma unroll 7
  for (int c = h; c < NCH; c += 2)
    sum += partial[((size_t)b * NCH + c) * K + k];

  __shared__ float vals[256];
  __shared__ int   idxs[K];
  vals[tid] = sum;
  __syncthreads();

  if (tid < K) { vals[tid] = vals[tid] + vals[tid + K]; idxs[tid] = tid; }
  __syncthreads();

  for (int off = K / 2; off > 0; off >>= 1) {
    if (tid < off) {
      const float o = vals[tid + off];
      if (o < vals[tid] || (o == vals[tid] && idxs[tid + off] < idxs[tid])) {
        vals[tid] = o; idxs[tid] = idxs[tid + off];
      }
    }
    __syncthreads();
  }

  const int best = idxs[0];
  if (tid < 16) out[(size_t)b * 16 + tid] = T[(size_t)(b * K + best) * 16 + tid];
}

// ---------------------------------------------------------------------------
extern "C" void kernel_launch(void* const* d_in, const int* in_sizes, int n_in,
                              void* d_out, int out_size, void* d_ws, size_t ws_size,
                              hipStream_t stream) {
  const float* src = (const float*)d_in[0];
  const float* tgt = (const float*)d_in[1];
  const float* wts = (const float*)d_in[2];
  const int*   sel = (const int*)d_in[3];

  const size_t part_floats    = (size_t)B * SLICES * K * 16;   // 1.05M floats
  const size_t T_floats       = (size_t)B * K * 16;            // 8192
  const size_t partial_floats = (size_t)B * NCH * K;           // 100352
  const bool fast = ws_size >=
      (part_floats + T_floats + partial_floats) * sizeof(float);

  if (fast) {
    float* part    = (float*)d_ws;
    float* T       = part + part_floats;
    float* partial = T + T_floats;

    scan_kernel<<<B * SLICES, 256, 0, stream>>>(src, tgt, wts, sel, part);
    reduce_solve_kernel<<<B * K, 256, 0, stream>>>(part, T);
    error_kernel<<<B * NCH, 256, 0, stream>>>(src, tgt, wts, T, partial);
    argmin_kernel<<<B, 256, 0, stream>>>(partial, T, (float*)d_out);
  } else {
    float* T       = (float*)d_ws;
    float* partial = T + T_floats;

    gather_reduce_kernel<<<B * K, 256, 0, stream>>>(src, tgt, wts, sel, T);
    error_kernel<<<B * NCH, 256, 0, stream>>>(src, tgt, wts, T, partial);
    argmin_kernel<<<B, 256, 0, stream>>>(partial, T, (float*)d_out);
  }
}

// Round 6
// 43.751 us; speedup vs baseline: 1.5056x; 1.4915x over previous
//
#include <hip/hip_runtime.h>
#include <hip/hip_bf16.h>

constexpr int B = 4;
constexpr int N = 50000;
constexpr int K = 128;
constexpr int S = 256;
constexpr int NCH = (N + 255) / 256;     // 196 chunks for error kernel
constexpr float EPS = 1e-5f;

__device__ __forceinline__ float frcp  (float x) { return __builtin_amdgcn_rcpf(x); }
__device__ __forceinline__ float frsq  (float x) { return __builtin_amdgcn_rsqf(x); }
__device__ __forceinline__ float fsqrt_(float x) { return __builtin_amdgcn_sqrtf(x); }

// ---------------------------------------------------------------------------
// Static-indexed Jacobi solve (registers only — rule #20)
// ---------------------------------------------------------------------------
template<int P, int Q>
__device__ __forceinline__ void rot(float (&A)[4][4], float (&V)[4][4])
{
  const float apq = A[P][Q];
  const float theta = 0.5f * (A[Q][Q] - A[P][P]) * frcp(apq);
  const float tt = copysignf(
      frcp(fabsf(theta) + fsqrt_(fmaf(theta, theta, 1.f))), theta);
  float c  = frsq(fmaf(tt, tt, 1.f));
  float sn = tt * c;
  const bool tiny = fabsf(apq) < 1e-20f;
  c  = tiny ? 1.f : c;
  sn = tiny ? 0.f : sn;
  #pragma unroll
  for (int i = 0; i < 4; ++i) {
    const float aip = A[i][P], aiq = A[i][Q];
    A[i][P] = c * aip - sn * aiq;
    A[i][Q] = sn * aip + c * aiq;
  }
  #pragma unroll
  for (int i = 0; i < 4; ++i) {
    const float api = A[P][i], aqi = A[Q][i];
    A[P][i] = c * api - sn * aqi;
    A[Q][i] = sn * api + c * aqi;
  }
  #pragma unroll
  for (int i = 0; i < 4; ++i) {
    const float vip = V[i][P], viq = V[i][Q];
    V[i][P] = c * vip - sn * viq;
    V[i][Q] = sn * vip + c * viq;
  }
}

// Sm = {W, Σwp(3), Σwq(3), Σw p⊗q(9)}  ->  write 4x4 transform at To
__device__ __forceinline__ void solve_and_write(const float (&Sm)[16], float* To)
{
  const float W   = Sm[0];
  const float inv = frcp(W + EPS);
  const float scx = Sm[1]*inv, scy = Sm[2]*inv, scz = Sm[3]*inv;
  const float tcx = Sm[4]*inv, tcy = Sm[5]*inv, tcz = Sm[6]*inv;
  const float f = 2.f - W * inv;     // H = Σ(w s⊗t)·inv − (2−σ)·sc⊗tc
  const float Sxx = Sm[7]*inv  - f*scx*tcx;
  const float Sxy = Sm[8]*inv  - f*scx*tcy;
  const float Sxz = Sm[9]*inv  - f*scx*tcz;
  const float Syx = Sm[10]*inv - f*scy*tcx;
  const float Syy = Sm[11]*inv - f*scy*tcy;
  const float Syz = Sm[12]*inv - f*scy*tcz;
  const float Szx = Sm[13]*inv - f*scz*tcx;
  const float Szy = Sm[14]*inv - f*scz*tcy;
  const float Szz = Sm[15]*inv - f*scz*tcz;

  float A[4][4], V[4][4];
  A[0][0] = Sxx + Syy + Szz;
  A[0][1] = Syz - Szy;  A[0][2] = Szx - Sxz;  A[0][3] = Sxy - Syx;
  A[1][1] = Sxx - Syy - Szz;
  A[1][2] = Sxy + Syx;  A[1][3] = Szx + Sxz;
  A[2][2] = -Sxx + Syy - Szz;
  A[2][3] = Syz + Szy;
  A[3][3] = -Sxx - Syy + Szz;
  A[1][0] = A[0][1]; A[2][0] = A[0][2]; A[3][0] = A[0][3];
  A[2][1] = A[1][2]; A[3][1] = A[1][3]; A[3][2] = A[2][3];

  #pragma unroll
  for (int i = 0; i < 4; ++i)
    #pragma unroll
    for (int j = 0; j < 4; ++j) V[i][j] = (i == j) ? 1.f : 0.f;

  #pragma unroll 1
  for (int sweep = 0; sweep < 5; ++sweep) {
    rot<0,1>(A, V); rot<0,2>(A, V); rot<0,3>(A, V);
    rot<1,2>(A, V); rot<1,3>(A, V); rot<2,3>(A, V);
  }

  const float d0 = A[0][0], d1 = A[1][1], d2 = A[2][2], d3 = A[3][3];
  const bool b1 = d1 > d0;
  const bool b3 = d3 > d2;
  const bool bb = (b3 ? d3 : d2) > (b1 ? d1 : d0);
  float qw  = bb ? (b3 ? V[0][3] : V[0][2]) : (b1 ? V[0][1] : V[0][0]);
  float qxv = bb ? (b3 ? V[1][3] : V[1][2]) : (b1 ? V[1][1] : V[1][0]);
  float qyv = bb ? (b3 ? V[2][3] : V[2][2]) : (b1 ? V[2][1] : V[2][0]);
  float qzv = bb ? (b3 ? V[3][3] : V[3][2]) : (b1 ? V[3][1] : V[3][0]);

  const float qn = frsq(qw*qw + qxv*qxv + qyv*qyv + qzv*qzv);
  qw *= qn; qxv *= qn; qyv *= qn; qzv *= qn;

  const float R00 = 1.f - 2.f*(qyv*qyv + qzv*qzv);
  const float R01 = 2.f*(qxv*qyv - qw*qzv);
  const float R02 = 2.f*(qxv*qzv + qw*qyv);
  const float R10 = 2.f*(qxv*qyv + qw*qzv);
  const float R11 = 1.f - 2.f*(qxv*qxv + qzv*qzv);
  const float R12 = 2.f*(qyv*qzv - qw*qxv);
  const float R20 = 2.f*(qxv*qzv - qw*qyv);
  const float R21 = 2.f*(qyv*qzv + qw*qxv);
  const float R22 = 1.f - 2.f*(qxv*qxv + qyv*qyv);

  const float tx = tcx - (R00*scx + R01*scy + R02*scz);
  const float ty = tcy - (R10*scx + R11*scy + R12*scz);
  const float tz = tcz - (R20*scx + R21*scy + R22*scz);

  float4* T4 = (float4*)To;
  T4[0] = make_float4(R00, R01, R02, tx);
  T4[1] = make_float4(R10, R11, R12, ty);
  T4[2] = make_float4(R20, R21, R22, tz);
  T4[3] = make_float4(0.f, 0.f, 0.f, 1.f);
}

// ---------------------------------------------------------------------------
// Kernel 0: interleaved pack. Record-group for point n = 4 batches x 32B
// {(p.xyz,w),(q.xyz,0)} contiguous = 128B = exactly 2 cache lines, so one
// (k,s) gather serves ALL 4 batches from 2 fully-utilized lines (R3 layout
// needed 4 half-utilized lines). Writes perfectly coalesced (128B/thread).
// ---------------------------------------------------------------------------
__global__ __launch_bounds__(256) void pack_kernel(
    const float* __restrict__ src, const float* __restrict__ tgt,
    const float* __restrict__ wts, float4* __restrict__ packed)
{
  const int n = blockIdx.x * 256 + threadIdx.x;
  if (n >= N) return;
  float4 rec[8];
  #pragma unroll
  for (int b = 0; b < B; ++b) {
    const int i = b * N + n;
    rec[b*2]   = make_float4(src[3*i], src[3*i+1], src[3*i+2], wts[i]);
    rec[b*2+1] = make_float4(tgt[3*i], tgt[3*i+1], tgt[3*i+2], 0.f);
  }
  float4* out = packed + (size_t)n * 8;
  #pragma unroll
  for (int r = 0; r < 8; ++r) out[r] = rec[r];
}

// ---------------------------------------------------------------------------
// Kernel 1: fused gather + reduce + static-register solve.
// Block = k (128 blocks x 1024 threads); thread = (s = tid>>2, b = tid&3).
// Lanes b=0..3 of one s read one contiguous 128B record-group (perfectly
// coalesced scatter: 2 full lines per (k,s), 65536 lines chip-wide).
// Shuffle-reduce over s (stride-4 lanes), LDS-combine over 16 waves, then
// lanes 0-3 run the register-only Jacobi for their batch. No scratch
// (R2's 5%-occupancy straggler tail), no extra kernel + sums round-trip.
// ---------------------------------------------------------------------------
template<bool PACKED>
__global__ __launch_bounds__(1024) void gather_solve_kernel(
    const float4* __restrict__ packed,
    const float* __restrict__ src, const float* __restrict__ tgt,
    const float* __restrict__ wts, const int* __restrict__ sel,
    float* __restrict__ T)
{
  const int k   = blockIdx.x;
  const int tid = threadIdx.x;
  const int s   = tid >> 2;
  const int b   = tid & 3;

  const int idx = sel[k * S + s];

  float px, py, pz, qx, qy, qz, w;
  if (PACKED) {
    const float4 P = packed[(size_t)idx * 8 + b * 2];
    const float4 Q = packed[(size_t)idx * 8 + b * 2 + 1];
    px = P.x; py = P.y; pz = P.z; w = P.w;
    qx = Q.x; qy = Q.y; qz = Q.z;
  } else {
    const float* ps = src + (size_t)(b * N + idx) * 3;
    const float* pt = tgt + (size_t)(b * N + idx) * 3;
    w  = wts[b * N + idx];
    px = ps[0]; py = ps[1]; pz = ps[2];
    qx = pt[0]; qy = pt[1]; qz = pt[2];
  }

  float acc[16];
  acc[0] = w;
  acc[1] = w * px;  acc[2] = w * py;  acc[3] = w * pz;
  acc[4] = w * qx;  acc[5] = w * qy;  acc[6] = w * qz;
  acc[7]  = w * px * qx; acc[8]  = w * px * qy; acc[9]  = w * px * qz;
  acc[10] = w * py * qx; acc[11] = w * py * qy; acc[12] = w * py * qz;
  acc[13] = w * pz * qx; acc[14] = w * pz * qy; acc[15] = w * pz * qz;

  // reduce over s within the wave: lanes at stride 4 share b
  #pragma unroll
  for (int off = 32; off >= 4; off >>= 1) {
    #pragma unroll
    for (int i = 0; i < 16; ++i)
      acc[i] += __shfl_down(acc[i], off);
  }

  __shared__ float red[16][4][16];   // [wave][batch][moment]
  __shared__ float SmS[4][17];
  const int lane = tid & 63, wv = tid >> 6;
  if (lane < 4) {
    #pragma unroll
    for (int i = 0; i < 16; ++i) red[wv][lane][i] = acc[i];
  }
  __syncthreads();

  if (tid < 64) {                    // (b,m) pairs; fixed-order 16-wave sum
    const int bb = tid >> 4, m = tid & 15;
    float t = 0.f;
    #pragma unroll
    for (int wgi = 0; wgi < 16; ++wgi) t += red[wgi][bb][m];
    SmS[bb][m] = t;
  }
  __syncthreads();

  if (tid < 4) {                     // 4 register-only solves, lanes 0-3
    float Sm[16];
    #pragma unroll
    for (int z = 0; z < 16; ++z) Sm[z] = SmS[tid][z];
    solve_and_write(Sm, T + (size_t)(tid * K + k) * 16);
  }
}

// ---------------------------------------------------------------------------
// Kernel 2: error evaluation (byte-identical to R5; ~VALU roofline)
// ---------------------------------------------------------------------------
constexpr int KPT = 4;
constexpr int KG  = K / KPT;      // 32
constexpr int NSL = 256 / KG;     // 8
constexpr int PPS = 256 / NSL;    // 32

__global__ __launch_bounds__(256) void error_kernel(
    const float* __restrict__ src, const float* __restrict__ tgt,
    const float* __restrict__ wts, const float* __restrict__ T,
    float* __restrict__ partial)
{
  __shared__ float4 sp[256];
  __shared__ float4 sq[256];
  __shared__ float  t4[K][12];
  __shared__ float  red[K][NSL + 1];

  const int blk = blockIdx.x;
  const int b   = blk / NCH;
  const int ch  = blk - b * NCH;
  const int tid = threadIdx.x;
  const int j   = ch * 256 + tid;

  float4 P = make_float4(0.f, 0.f, 0.f, 0.f);
  float4 Q = make_float4(0.f, 0.f, 0.f, 0.f);
  if (j < N) {
    const float* ps = src + (size_t)(b*N + j) * 3;
    const float* pt = tgt + (size_t)(b*N + j) * 3;
    P.x = ps[0]; P.y = ps[1]; P.z = ps[2]; P.w = wts[b*N + j];
    Q.x = pt[0]; Q.y = pt[1]; Q.z = pt[2];
  }
  sp[tid] = P; sq[tid] = Q;

  if (tid < K) {
    const float* tp = T + (size_t)(b*K + tid) * 16;
    #pragma unroll
    for (int c = 0; c < 12; ++c) t4[tid][c] = tp[c];
  }
  __syncthreads();

  const int kg    = tid & (KG - 1);
  const int slice = tid >> 5;

  float R[KPT][12];
  #pragma unroll
  for (int m = 0; m < KPT; ++m) {
    const int k = kg + m * KG;
    #pragma unroll
    for (int c = 0; c < 12; ++c) R[m][c] = t4[k][c];
  }

  float acc[KPT] = {0.f, 0.f, 0.f, 0.f};
  const int base = slice * PPS;
  #pragma unroll 4
  for (int i = 0; i < PPS; ++i) {
    const float4 p = sp[base + i];
    const float4 q = sq[base + i];
    #pragma unroll
    for (int m = 0; m < KPT; ++m) {
      const float dx = fmaf(R[m][0], p.x, fmaf(R[m][1], p.y, fmaf(R[m][2],  p.z, R[m][3])))  - q.x;
      const float dy = fmaf(R[m][4], p.x, fmaf(R[m][5], p.y, fmaf(R[m][6],  p.z, R[m][7])))  - q.y;
      const float dz = fmaf(R[m][8], p.x, fmaf(R[m][9], p.y, fmaf(R[m][10], p.z, R[m][11]))) - q.z;
      const float d2 = fmaf(dx, dx, fmaf(dy, dy, dz*dz));
      acc[m] = fmaf(p.w, fsqrt_(d2), acc[m]);
    }
  }

  #pragma unroll
  for (int m = 0; m < KPT; ++m)
    red[kg + m * KG][slice] = acc[m];
  __syncthreads();

  if (tid < K) {
    float sum = 0.f;
    #pragma unroll
    for (int s2 = 0; s2 < NSL; ++s2) sum += red[tid][s2];
    partial[((size_t)b * NCH + ch) * K + tid] = sum;
  }
}

// ---------------------------------------------------------------------------
// Kernel 3: argmin (byte-identical to R5)
// ---------------------------------------------------------------------------
__global__ __launch_bounds__(256) void argmin_kernel(
    const float* __restrict__ partial, const float* __restrict__ T,
    float* __restrict__ out)
{
  const int b   = blockIdx.x;
  const int tid = threadIdx.x;
  const int k   = tid & (K - 1);
  const int h   = tid >> 7;

  float sum = 0.f;
  #pragma unroll 7
  for (int c = h; c < NCH; c += 2)
    sum += partial[((size_t)b * NCH + c) * K + k];

  __shared__ float vals[256];
  __shared__ int   idxs[K];
  vals[tid] = sum;
  __syncthreads();

  if (tid < K) { vals[tid] = vals[tid] + vals[tid + K]; idxs[tid] = tid; }
  __syncthreads();

  for (int off = K / 2; off > 0; off >>= 1) {
    if (tid < off) {
      const float o = vals[tid + off];
      if (o < vals[tid] || (o == vals[tid] && idxs[tid + off] < idxs[tid])) {
        vals[tid] = o; idxs[tid] = idxs[tid + off];
      }
    }
    __syncthreads();
  }

  const int best = idxs[0];
  if (tid < 16) out[(size_t)b * 16 + tid] = T[(size_t)(b * K + best) * 16 + tid];
}

// ---------------------------------------------------------------------------
extern "C" void kernel_launch(void* const* d_in, const int* in_sizes, int n_in,
                              void* d_out, int out_size, void* d_ws, size_t ws_size,
                              hipStream_t stream) {
  const float* src = (const float*)d_in[0];
  const float* tgt = (const float*)d_in[1];
  const float* wts = (const float*)d_in[2];
  const int*   sel = (const int*)d_in[3];

  const size_t packed_bytes   = (size_t)N * 8 * sizeof(float4);   // 6.4 MB
  const size_t T_floats       = (size_t)B * K * 16;               // 8192
  const size_t partial_floats = (size_t)B * NCH * K;              // 100352
  const bool fast = ws_size >=
      packed_bytes + (T_floats + partial_floats) * sizeof(float);

  if (fast) {
    float4* packed  = (float4*)d_ws;
    float*  T       = (float*)((char*)d_ws + packed_bytes);
    float*  partial = T + T_floats;

    pack_kernel<<<(N + 255) / 256, 256, 0, stream>>>(src, tgt, wts, packed);
    gather_solve_kernel<true><<<K, 1024, 0, stream>>>(
        packed, src, tgt, wts, sel, T);
    error_kernel<<<B * NCH, 256, 0, stream>>>(src, tgt, wts, T, partial);
    argmin_kernel<<<B, 256, 0, stream>>>(partial, T, (float*)d_out);
  } else {
    float* T       = (float*)d_ws;
    float* partial = T + T_floats;

    gather_solve_kernel<false><<<K, 1024, 0, stream>>>(
        nullptr, src, tgt, wts, sel, T);
    error_kernel<<<B * NCH, 256, 0, stream>>>(src, tgt, wts, T, partial);
    argmin_kernel<<<B, 256, 0, stream>>>(partial, T, (float*)d_out);
  }
}

// Round 7
// 43.576 us; speedup vs baseline: 1.5117x; 1.0040x over previous
//
#include <hip/hip_runtime.h>
#include <hip/hip_bf16.h>

constexpr int B = 4;
constexpr int N = 50000;
constexpr int K = 128;
constexpr int S = 256;
constexpr int NCH = (N + 255) / 256;     // 196 chunks for error kernel
constexpr float EPS = 1e-5f;

__device__ __forceinline__ float frcp  (float x) { return __builtin_amdgcn_rcpf(x); }
__device__ __forceinline__ float frsq  (float x) { return __builtin_amdgcn_rsqf(x); }
__device__ __forceinline__ float fsqrt_(float x) { return __builtin_amdgcn_sqrtf(x); }

// ---------------------------------------------------------------------------
// Static-indexed Jacobi solve (registers only — rule #20)
// ---------------------------------------------------------------------------
template<int P, int Q>
__device__ __forceinline__ void rot(float (&A)[4][4], float (&V)[4][4])
{
  const float apq = A[P][Q];
  const float theta = 0.5f * (A[Q][Q] - A[P][P]) * frcp(apq);
  const float tt = copysignf(
      frcp(fabsf(theta) + fsqrt_(fmaf(theta, theta, 1.f))), theta);
  float c  = frsq(fmaf(tt, tt, 1.f));
  float sn = tt * c;
  const bool tiny = fabsf(apq) < 1e-20f;
  c  = tiny ? 1.f : c;
  sn = tiny ? 0.f : sn;
  #pragma unroll
  for (int i = 0; i < 4; ++i) {
    const float aip = A[i][P], aiq = A[i][Q];
    A[i][P] = c * aip - sn * aiq;
    A[i][Q] = sn * aip + c * aiq;
  }
  #pragma unroll
  for (int i = 0; i < 4; ++i) {
    const float api = A[P][i], aqi = A[Q][i];
    A[P][i] = c * api - sn * aqi;
    A[Q][i] = sn * api + c * aqi;
  }
  #pragma unroll
  for (int i = 0; i < 4; ++i) {
    const float vip = V[i][P], viq = V[i][Q];
    V[i][P] = c * vip - sn * viq;
    V[i][Q] = sn * vip + c * viq;
  }
}

// Sm = {W, Σwp(3), Σwq(3), Σw p⊗q(9)}  ->  write 4x4 transform at To
__device__ __forceinline__ void solve_and_write(const float (&Sm)[16], float* To)
{
  const float W   = Sm[0];
  const float inv = frcp(W + EPS);
  const float scx = Sm[1]*inv, scy = Sm[2]*inv, scz = Sm[3]*inv;
  const float tcx = Sm[4]*inv, tcy = Sm[5]*inv, tcz = Sm[6]*inv;
  const float f = 2.f - W * inv;     // H = Σ(w s⊗t)·inv − (2−σ)·sc⊗tc
  const float Sxx = Sm[7]*inv  - f*scx*tcx;
  const float Sxy = Sm[8]*inv  - f*scx*tcy;
  const float Sxz = Sm[9]*inv  - f*scx*tcz;
  const float Syx = Sm[10]*inv - f*scy*tcx;
  const float Syy = Sm[11]*inv - f*scy*tcy;
  const float Syz = Sm[12]*inv - f*scy*tcz;
  const float Szx = Sm[13]*inv - f*scz*tcx;
  const float Szy = Sm[14]*inv - f*scz*tcy;
  const float Szz = Sm[15]*inv - f*scz*tcz;

  float A[4][4], V[4][4];
  A[0][0] = Sxx + Syy + Szz;
  A[0][1] = Syz - Szy;  A[0][2] = Szx - Sxz;  A[0][3] = Sxy - Syx;
  A[1][1] = Sxx - Syy - Szz;
  A[1][2] = Sxy + Syx;  A[1][3] = Szx + Sxz;
  A[2][2] = -Sxx + Syy - Szz;
  A[2][3] = Syz + Szy;
  A[3][3] = -Sxx - Syy + Szz;
  A[1][0] = A[0][1]; A[2][0] = A[0][2]; A[3][0] = A[0][3];
  A[2][1] = A[1][2]; A[3][1] = A[1][3]; A[3][2] = A[2][3];

  #pragma unroll
  for (int i = 0; i < 4; ++i)
    #pragma unroll
    for (int j = 0; j < 4; ++j) V[i][j] = (i == j) ? 1.f : 0.f;

  #pragma unroll 1
  for (int sweep = 0; sweep < 5; ++sweep) {
    rot<0,1>(A, V); rot<0,2>(A, V); rot<0,3>(A, V);
    rot<1,2>(A, V); rot<1,3>(A, V); rot<2,3>(A, V);
  }

  const float d0 = A[0][0], d1 = A[1][1], d2 = A[2][2], d3 = A[3][3];
  const bool b1 = d1 > d0;
  const bool b3 = d3 > d2;
  const bool bb = (b3 ? d3 : d2) > (b1 ? d1 : d0);
  float qw  = bb ? (b3 ? V[0][3] : V[0][2]) : (b1 ? V[0][1] : V[0][0]);
  float qxv = bb ? (b3 ? V[1][3] : V[1][2]) : (b1 ? V[1][1] : V[1][0]);
  float qyv = bb ? (b3 ? V[2][3] : V[2][2]) : (b1 ? V[2][1] : V[2][0]);
  float qzv = bb ? (b3 ? V[3][3] : V[3][2]) : (b1 ? V[3][1] : V[3][0]);

  const float qn = frsq(qw*qw + qxv*qxv + qyv*qyv + qzv*qzv);
  qw *= qn; qxv *= qn; qyv *= qn; qzv *= qn;

  const float R00 = 1.f - 2.f*(qyv*qyv + qzv*qzv);
  const float R01 = 2.f*(qxv*qyv - qw*qzv);
  const float R02 = 2.f*(qxv*qzv + qw*qyv);
  const float R10 = 2.f*(qxv*qyv + qw*qzv);
  const float R11 = 1.f - 2.f*(qxv*qxv + qzv*qzv);
  const float R12 = 2.f*(qyv*qzv - qw*qxv);
  const float R20 = 2.f*(qxv*qzv - qw*qyv);
  const float R21 = 2.f*(qyv*qzv + qw*qxv);
  const float R22 = 1.f - 2.f*(qxv*qxv + qyv*qyv);

  const float tx = tcx - (R00*scx + R01*scy + R02*scz);
  const float ty = tcy - (R10*scx + R11*scy + R12*scz);
  const float tz = tcz - (R20*scx + R21*scy + R22*scz);

  float4* T4 = (float4*)To;
  T4[0] = make_float4(R00, R01, R02, tx);
  T4[1] = make_float4(R10, R11, R12, ty);
  T4[2] = make_float4(R20, R21, R22, tz);
  T4[3] = make_float4(0.f, 0.f, 0.f, 1.f);
}

// ---------------------------------------------------------------------------
// Kernel 1: single fused fit kernel, RAW inputs (no pack kernel, no packed
// array). Block = (b,k), XCD-pinned so each block's batch working set
// (src+tgt+wts = 1.4MB) fits ENTIRELY in its XCD's 4MB L2 — steady-state
// replays serve the whole scattered gather from local L2, no L3.
// 256 threads gather one sample each, shuffle+LDS reduce the 16 moments,
// thread 0 runs the static-register Jacobi (R6-proven, no scratch).
// ---------------------------------------------------------------------------
__global__ __launch_bounds__(256) void gather_solve_kernel(
    const float* __restrict__ src, const float* __restrict__ tgt,
    const float* __restrict__ wts, const int* __restrict__ sel,
    float* __restrict__ T)
{
  const int bid = blockIdx.x;
  const int xcd = bid & 7;
  const int b   = xcd >> 1;                       // batch pinned to XCD pair
  const int k   = ((bid >> 3) << 1) | (xcd & 1);  // bijective over [0,128)
  const int s   = threadIdx.x;

  const int idx = sel[k * S + s];
  const float* ps = src + (size_t)(b * N + idx) * 3;
  const float* pt = tgt + (size_t)(b * N + idx) * 3;
  const float w  = wts[b * N + idx];
  const float px = ps[0], py = ps[1], pz = ps[2];
  const float qx = pt[0], qy = pt[1], qz = pt[2];

  float acc[16];
  acc[0] = w;
  acc[1] = w * px;  acc[2] = w * py;  acc[3] = w * pz;
  acc[4] = w * qx;  acc[5] = w * qy;  acc[6] = w * qz;
  acc[7]  = w * px * qx; acc[8]  = w * px * qy; acc[9]  = w * px * qz;
  acc[10] = w * py * qx; acc[11] = w * py * qy; acc[12] = w * py * qz;
  acc[13] = w * pz * qx; acc[14] = w * pz * qy; acc[15] = w * pz * qz;

  #pragma unroll
  for (int off = 32; off > 0; off >>= 1) {
    #pragma unroll
    for (int i = 0; i < 16; ++i)
      acc[i] += __shfl_down(acc[i], off);
  }

  __shared__ float red[4][16];
  const int lane = threadIdx.x & 63, wv = threadIdx.x >> 6;
  if (lane == 0) {
    #pragma unroll
    for (int i = 0; i < 16; ++i) red[wv][i] = acc[i];
  }
  __syncthreads();

  if (threadIdx.x == 0) {
    float Sm[16];
    #pragma unroll
    for (int i = 0; i < 16; ++i)
      Sm[i] = red[0][i] + red[1][i] + red[2][i] + red[3][i];
    solve_and_write(Sm, T + (size_t)(b * K + k) * 16);   // register-only solve
  }
}

// ---------------------------------------------------------------------------
// Kernel 2: error evaluation (byte-identical to R5/R6; ~VALU roofline)
// ---------------------------------------------------------------------------
constexpr int KPT = 4;
constexpr int KG  = K / KPT;      // 32
constexpr int NSL = 256 / KG;     // 8
constexpr int PPS = 256 / NSL;    // 32

__global__ __launch_bounds__(256) void error_kernel(
    const float* __restrict__ src, const float* __restrict__ tgt,
    const float* __restrict__ wts, const float* __restrict__ T,
    float* __restrict__ partial)
{
  __shared__ float4 sp[256];
  __shared__ float4 sq[256];
  __shared__ float  t4[K][12];
  __shared__ float  red[K][NSL + 1];

  const int blk = blockIdx.x;
  const int b   = blk / NCH;
  const int ch  = blk - b * NCH;
  const int tid = threadIdx.x;
  const int j   = ch * 256 + tid;

  float4 P = make_float4(0.f, 0.f, 0.f, 0.f);
  float4 Q = make_float4(0.f, 0.f, 0.f, 0.f);
  if (j < N) {
    const float* ps = src + (size_t)(b*N + j) * 3;
    const float* pt = tgt + (size_t)(b*N + j) * 3;
    P.x = ps[0]; P.y = ps[1]; P.z = ps[2]; P.w = wts[b*N + j];
    Q.x = pt[0]; Q.y = pt[1]; Q.z = pt[2];
  }
  sp[tid] = P; sq[tid] = Q;

  if (tid < K) {
    const float* tp = T + (size_t)(b*K + tid) * 16;
    #pragma unroll
    for (int c = 0; c < 12; ++c) t4[tid][c] = tp[c];
  }
  __syncthreads();

  const int kg    = tid & (KG - 1);
  const int slice = tid >> 5;

  float R[KPT][12];
  #pragma unroll
  for (int m = 0; m < KPT; ++m) {
    const int k = kg + m * KG;
    #pragma unroll
    for (int c = 0; c < 12; ++c) R[m][c] = t4[k][c];
  }

  float acc[KPT] = {0.f, 0.f, 0.f, 0.f};
  const int base = slice * PPS;
  #pragma unroll 4
  for (int i = 0; i < PPS; ++i) {
    const float4 p = sp[base + i];
    const float4 q = sq[base + i];
    #pragma unroll
    for (int m = 0; m < KPT; ++m) {
      const float dx = fmaf(R[m][0], p.x, fmaf(R[m][1], p.y, fmaf(R[m][2],  p.z, R[m][3])))  - q.x;
      const float dy = fmaf(R[m][4], p.x, fmaf(R[m][5], p.y, fmaf(R[m][6],  p.z, R[m][7])))  - q.y;
      const float dz = fmaf(R[m][8], p.x, fmaf(R[m][9], p.y, fmaf(R[m][10], p.z, R[m][11]))) - q.z;
      const float d2 = fmaf(dx, dx, fmaf(dy, dy, dz*dz));
      acc[m] = fmaf(p.w, fsqrt_(d2), acc[m]);
    }
  }

  #pragma unroll
  for (int m = 0; m < KPT; ++m)
    red[kg + m * KG][slice] = acc[m];
  __syncthreads();

  if (tid < K) {
    float sum = 0.f;
    #pragma unroll
    for (int s2 = 0; s2 < NSL; ++s2) sum += red[tid][s2];
    partial[((size_t)b * NCH + ch) * K + tid] = sum;
  }
}

// ---------------------------------------------------------------------------
// Kernel 3: argmin (byte-identical to R5/R6)
// ---------------------------------------------------------------------------
__global__ __launch_bounds__(256) void argmin_kernel(
    const float* __restrict__ partial, const float* __restrict__ T,
    float* __restrict__ out)
{
  const int b   = blockIdx.x;
  const int tid = threadIdx.x;
  const int k   = tid & (K - 1);
  const int h   = tid >> 7;

  float sum = 0.f;
  #pragma unroll 7
  for (int c = h; c < NCH; c += 2)
    sum += partial[((size_t)b * NCH + c) * K + k];

  __shared__ float vals[256];
  __shared__ int   idxs[K];
  vals[tid] = sum;
  __syncthreads();

  if (tid < K) { vals[tid] = vals[tid] + vals[tid + K]; idxs[tid] = tid; }
  __syncthreads();

  for (int off = K / 2; off > 0; off >>= 1) {
    if (tid < off) {
      const float o = vals[tid + off];
      if (o < vals[tid] || (o == vals[tid] && idxs[tid + off] < idxs[tid])) {
        vals[tid] = o; idxs[tid] = idxs[tid + off];
      }
    }
    __syncthreads();
  }

  const int best = idxs[0];
  if (tid < 16) out[(size_t)b * 16 + tid] = T[(size_t)(b * K + best) * 16 + tid];
}

// ---------------------------------------------------------------------------
extern "C" void kernel_launch(void* const* d_in, const int* in_sizes, int n_in,
                              void* d_out, int out_size, void* d_ws, size_t ws_size,
                              hipStream_t stream) {
  const float* src = (const float*)d_in[0];
  const float* tgt = (const float*)d_in[1];
  const float* wts = (const float*)d_in[2];
  const int*   sel = (const int*)d_in[3];

  float* T       = (float*)d_ws;                 // B*K*16 floats
  float* partial = T + (size_t)B * K * 16;       // B*NCH*K floats

  gather_solve_kernel<<<B * K, 256, 0, stream>>>(src, tgt, wts, sel, T);
  error_kernel<<<B * NCH, 256, 0, stream>>>(src, tgt, wts, T, partial);
  argmin_kernel<<<B, 256, 0, stream>>>(partial, T, (float*)d_out);
}